// Round 1
// baseline (606.028 us; speedup 1.0000x reference)
//
#include <hip/hip_runtime.h>

#define NN 10000
#define EE 100000
#define CC 32
#define GG 64
#define EPSV 1e-5f
#define PROW 33          // 32 h-rows + 1 bias row
#define PSTRIDE (PROW*32)  // 1056 floats per node

// ---------------- degree / pool-count histograms ----------------
__global__ void k_degrees(const int* __restrict__ ei, const int* __restrict__ batch,
                          int* __restrict__ cnt, int* __restrict__ pcnt) {
    int t = blockIdx.x * blockDim.x + threadIdx.x;
    if (t < EE) atomicAdd(&cnt[ei[EE + t]], 1);   // dst in-degree
    if (t < NN) atomicAdd(&pcnt[batch[t]], 1);    // nodes per graph
}

// ---------------- P[n,c,o] = sum_i x[n,i]*w2[c,i*32+o]; row 32 = bias row ----------------
__global__ __launch_bounds__(256) void k_precompute(const float* __restrict__ x,
        const float* __restrict__ w2, const float* __restrict__ b2,
        float* __restrict__ P) {
    __shared__ float xs[8][32];
    int t = threadIdx.x;
    int n0 = blockIdx.x * 8;
    xs[t >> 5][t & 31] = x[n0 * 32 + t];
    __syncthreads();
    for (int slot = t; slot < PSTRIDE; slot += 256) {
        int c = slot >> 5, o = slot & 31;
        const float* wrow = (c < 32) ? (w2 + c * 1024) : b2;
        float acc[8];
        #pragma unroll
        for (int k = 0; k < 8; k++) acc[k] = 0.f;
        for (int i = 0; i < 32; i++) {
            float wv = wrow[i * 32 + o];
            #pragma unroll
            for (int k = 0; k < 8; k++) acc[k] += xs[k][i] * wv;
        }
        #pragma unroll
        for (int k = 0; k < 8; k++) P[(size_t)(n0 + k) * PSTRIDE + slot] = acc[k];
    }
}

// ---------------- per-edge message + atomic scatter to agg[dst] ----------------
// half-wave (32 lanes) per edge; lane = output channel o; h computed on the fly
__global__ __launch_bounds__(256) void k_message(const float* __restrict__ edge_attr,
        const float* __restrict__ w1, const float* __restrict__ b1,
        const float* __restrict__ P, const int* __restrict__ ei,
        float* __restrict__ agg) {
    int t = threadIdx.x;
    int e = blockIdx.x * 8 + (t >> 5);
    int o = t & 31;
    if (e >= EE) return;
    const float* ea = edge_attr + (size_t)e * 4;
    float h = ea[0] * w1[o] + ea[1] * w1[32 + o] + ea[2] * w1[64 + o] + ea[3] * w1[96 + o] + b1[o];
    h = fmaxf(h, 0.f);
    int src = ei[e], dst = ei[EE + e];
    const float* Pn = P + (size_t)src * PSTRIDE;
    float msg = Pn[32 * 32 + o];          // bias row
    #pragma unroll
    for (int c = 0; c < 32; c++) {
        float hc = __shfl(h, c, 32);      // broadcast h[c] within the 32-lane half
        msg += hc * Pn[c * 32 + o];
    }
    atomicAdd(&agg[(size_t)dst * 32 + o], msg);
}

// ---------------- combine: agg/cnt + x@root + bias -> BN -> ReLU ----------------
__global__ __launch_bounds__(256) void k_combine(const float* __restrict__ x_in,
        const float* __restrict__ agg, const int* __restrict__ cnt,
        const float* __restrict__ root, const float* __restrict__ bias,
        const float* __restrict__ bng, const float* __restrict__ bnb,
        const float* __restrict__ bnm, const float* __restrict__ bnv,
        float* __restrict__ x_out, float* __restrict__ psum,
        const int* __restrict__ batch) {
    __shared__ float xs[8][32];
    int t = threadIdx.x;
    int n0 = blockIdx.x * 8;
    xs[t >> 5][t & 31] = x_in[n0 * 32 + t];
    __syncthreads();
    int k = t >> 5, o = t & 31, n = n0 + k;
    float r = bias[o];
    #pragma unroll
    for (int i = 0; i < 32; i++) r += xs[k][i] * root[i * 32 + o];
    float a = agg[(size_t)n * 32 + o] / fmaxf((float)cnt[n], 1.f);
    float val = a + r;
    val = (val - bnm[o]) * rsqrtf(bnv[o] + EPSV) * bng[o] + bnb[o];
    val = fmaxf(val, 0.f);
    if (x_out) x_out[(size_t)n * 32 + o] = val;
    if (psum) atomicAdd(&psum[(size_t)batch[n] * 32 + o], val);
}

// ---------------- global mean pool (counts) + readout MLP ----------------
__global__ void k_readout(const float* __restrict__ psum, const int* __restrict__ pcnt,
        const float* __restrict__ r1w, const float* __restrict__ r1b,
        const float* __restrict__ r2w, const float* __restrict__ r2b,
        float* __restrict__ out) {
    int g = threadIdx.x;
    if (g >= GG) return;
    float inv = 1.f / fmaxf((float)pcnt[g], 1.f);
    float pooled[32];
    #pragma unroll
    for (int c = 0; c < 32; c++) pooled[c] = psum[g * 32 + c] * inv;
    float acc = r2b[0];
    #pragma unroll
    for (int j = 0; j < 16; j++) {
        float z = r1b[j];
        #pragma unroll
        for (int c = 0; c < 32; c++) z += pooled[c] * r1w[c * 16 + j];
        z = fmaxf(z, 0.f);
        acc += z * r2w[j];
    }
    out[g] = acc;
}

extern "C" void kernel_launch(void* const* d_in, const int* in_sizes, int n_in,
                              void* d_out, int out_size, void* d_ws, size_t ws_size,
                              hipStream_t stream) {
    const float* x       = (const float*)d_in[0];
    const float* eattr   = (const float*)d_in[1];
    const float* e1_w1   = (const float*)d_in[2];
    const float* e1_b1   = (const float*)d_in[3];
    const float* e1_w2   = (const float*)d_in[4];
    const float* e1_b2   = (const float*)d_in[5];
    const float* root1   = (const float*)d_in[6];
    const float* bias1   = (const float*)d_in[7];
    const float* e2_w1   = (const float*)d_in[8];
    const float* e2_b1   = (const float*)d_in[9];
    const float* e2_w2   = (const float*)d_in[10];
    const float* e2_b2   = (const float*)d_in[11];
    const float* root2   = (const float*)d_in[12];
    const float* bias2   = (const float*)d_in[13];
    const float* bn1_g   = (const float*)d_in[14];
    const float* bn1_b   = (const float*)d_in[15];
    const float* bn1_m   = (const float*)d_in[16];
    const float* bn1_v   = (const float*)d_in[17];
    const float* bn2_g   = (const float*)d_in[18];
    const float* bn2_b   = (const float*)d_in[19];
    const float* bn2_m   = (const float*)d_in[20];
    const float* bn2_v   = (const float*)d_in[21];
    const float* r1_w    = (const float*)d_in[22];
    const float* r1_b    = (const float*)d_in[23];
    const float* r2_w    = (const float*)d_in[24];
    const float* r2_b    = (const float*)d_in[25];
    const int*   ei      = (const int*)d_in[26];
    const int*   batch   = (const int*)d_in[27];

    // workspace layout (bytes, 256-aligned)
    char* ws = (char*)d_ws;
    float* P    = (float*)(ws);                         // 10000*1056*4 = 42,240,000
    float* agg  = (float*)(ws + 42240000);              // 1,280,000
    float* xmid = (float*)(ws + 43520000);              // 1,280,000
    int*   cnt  = (int*)  (ws + 44800000);              // 40,000
    float* psum = (float*)(ws + 44840192);              // 8,192
    int*   pcnt = (int*)  (ws + 44848384);              // 256
    // total ~44.85 MB

    hipMemsetAsync(agg,  0, NN * 32 * 4, stream);
    hipMemsetAsync(cnt,  0, NN * 4, stream);
    hipMemsetAsync(psum, 0, GG * 32 * 4, stream);
    hipMemsetAsync(pcnt, 0, GG * 4, stream);

    k_degrees<<<(EE + 255) / 256, 256, 0, stream>>>(ei, batch, cnt, pcnt);

    // ---- layer 1 ----
    k_precompute<<<NN / 8, 256, 0, stream>>>(x, e1_w2, e1_b2, P);
    k_message<<<EE / 8, 256, 0, stream>>>(eattr, e1_w1, e1_b1, P, ei, agg);
    k_combine<<<NN / 8, 256, 0, stream>>>(x, agg, cnt, root1, bias1,
                                          bn1_g, bn1_b, bn1_m, bn1_v,
                                          xmid, nullptr, batch);

    // ---- layer 2 ----
    hipMemsetAsync(agg, 0, NN * 32 * 4, stream);
    k_precompute<<<NN / 8, 256, 0, stream>>>(xmid, e2_w2, e2_b2, P);
    k_message<<<EE / 8, 256, 0, stream>>>(eattr, e2_w1, e2_b1, P, ei, agg);
    k_combine<<<NN / 8, 256, 0, stream>>>(xmid, agg, cnt, root2, bias2,
                                          bn2_g, bn2_b, bn2_m, bn2_v,
                                          nullptr, psum, batch);

    // ---- pool + readout ----
    k_readout<<<1, 64, 0, stream>>>(psum, pcnt, r1_w, r1_b, r2_w, r2_b, (float*)d_out);
}

// Round 2
// 546.732 us; speedup vs baseline: 1.1085x; 1.1085x over previous
//
#include <hip/hip_runtime.h>

#define NN 10000
#define EE 100000
#define CC 32
#define GG 64
#define EPSV 1e-5f
#define PROW 33          // 32 h-rows + 1 bias row
#define PSTRIDE (PROW*32)  // 1056 floats per node

// ---------------- degree / pool-count histograms ----------------
__global__ void k_degrees(const int* __restrict__ ei, const int* __restrict__ batch,
                          int* __restrict__ cnt, int* __restrict__ pcnt) {
    int t = blockIdx.x * blockDim.x + threadIdx.x;
    if (t < EE) atomicAdd(&cnt[ei[EE + t]], 1);   // dst in-degree
    if (t < NN) atomicAdd(&pcnt[batch[t]], 1);    // nodes per graph
}

// ---------------- P[n,c,o] = sum_i x[n,i]*w2[c,i*32+o]; row 32 = bias row ----------------
__global__ __launch_bounds__(256) void k_precompute(const float* __restrict__ x,
        const float* __restrict__ w2, const float* __restrict__ b2,
        float* __restrict__ P) {
    __shared__ float xs[8][32];
    int t = threadIdx.x;
    int n0 = blockIdx.x * 8;
    xs[t >> 5][t & 31] = x[n0 * 32 + t];
    __syncthreads();
    for (int slot = t; slot < PSTRIDE; slot += 256) {
        int c = slot >> 5, o = slot & 31;
        const float* wrow = (c < 32) ? (w2 + c * 1024) : b2;
        float acc[8];
        #pragma unroll
        for (int k = 0; k < 8; k++) acc[k] = 0.f;
        for (int i = 0; i < 32; i++) {
            float wv = wrow[i * 32 + o];
            #pragma unroll
            for (int k = 0; k < 8; k++) acc[k] += xs[k][i] * wv;
        }
        #pragma unroll
        for (int k = 0; k < 8; k++) P[(size_t)(n0 + k) * PSTRIDE + slot] = acc[k];
    }
}

// ---------------- per-edge message + atomic scatter to agg[dst] ----------------
// half-wave (32 lanes) per edge; lane = output channel o; h computed on the fly
__global__ __launch_bounds__(256) void k_message(const float* __restrict__ edge_attr,
        const float* __restrict__ w1, const float* __restrict__ b1,
        const float* __restrict__ P, const int* __restrict__ ei,
        float* __restrict__ agg) {
    int t = threadIdx.x;
    int e = blockIdx.x * 8 + (t >> 5);
    int o = t & 31;
    if (e >= EE) return;
    const float* ea = edge_attr + (size_t)e * 4;
    float h = ea[0] * w1[o] + ea[1] * w1[32 + o] + ea[2] * w1[64 + o] + ea[3] * w1[96 + o] + b1[o];
    h = fmaxf(h, 0.f);
    int src = ei[e], dst = ei[EE + e];
    const float* Pn = P + (size_t)src * PSTRIDE;
    float msg = Pn[32 * 32 + o];          // bias row
    #pragma unroll
    for (int c = 0; c < 32; c++) {
        float hc = __shfl(h, c, 32);      // broadcast h[c] within the 32-lane half
        msg += hc * Pn[c * 32 + o];
    }
    atomicAdd(&agg[(size_t)dst * 32 + o], msg);
}

// ---------------- combine: agg/cnt + x@root + bias -> BN -> ReLU ----------------
__global__ __launch_bounds__(256) void k_combine(const float* __restrict__ x_in,
        const float* __restrict__ agg, const int* __restrict__ cnt,
        const float* __restrict__ root, const float* __restrict__ bias,
        const float* __restrict__ bng, const float* __restrict__ bnb,
        const float* __restrict__ bnm, const float* __restrict__ bnv,
        float* __restrict__ x_out, float* __restrict__ psum,
        const int* __restrict__ batch) {
    __shared__ float xs[8][32];
    int t = threadIdx.x;
    int n0 = blockIdx.x * 8;
    xs[t >> 5][t & 31] = x_in[n0 * 32 + t];
    __syncthreads();
    int k = t >> 5, o = t & 31, n = n0 + k;
    float r = bias[o];
    #pragma unroll
    for (int i = 0; i < 32; i++) r += xs[k][i] * root[i * 32 + o];
    float a = agg[(size_t)n * 32 + o] / fmaxf((float)cnt[n], 1.f);
    float val = a + r;
    val = (val - bnm[o]) * rsqrtf(bnv[o] + EPSV) * bng[o] + bnb[o];
    val = fmaxf(val, 0.f);
    if (x_out) x_out[(size_t)n * 32 + o] = val;
    if (psum) atomicAdd(&psum[(size_t)batch[n] * 32 + o], val);
}

// ---------------- global mean pool + readout MLP (LDS-staged, latency fix R1) ----------------
// R1: old version was 1 wave with rolled global-load loop -> ~512 serial ~400cy
// loads = 175 us. Stage all weights + psum into LDS with coalesced loads first.
__global__ __launch_bounds__(256) void k_readout(const float* __restrict__ psum,
        const int* __restrict__ pcnt,
        const float* __restrict__ r1w, const float* __restrict__ r1b,
        const float* __restrict__ r2w, const float* __restrict__ r2b,
        float* __restrict__ out) {
    __shared__ float w1s[32 * 16];
    __shared__ float b1s[16];
    __shared__ float w2s[16];
    __shared__ float ps[GG * 32];
    int t = threadIdx.x;
    w1s[t] = r1w[t];
    w1s[t + 256] = r1w[t + 256];
    if (t < 16) { b1s[t] = r1b[t]; w2s[t] = r2w[t]; }
    #pragma unroll
    for (int i = 0; i < GG * 32 / 256; i++) ps[t + i * 256] = psum[t + i * 256];
    __syncthreads();
    if (t < GG) {
        float inv = 1.f / fmaxf((float)pcnt[t], 1.f);
        float acc = r2b[0];
        #pragma unroll
        for (int j = 0; j < 16; j++) {
            float dot = 0.f;
            #pragma unroll
            for (int c = 0; c < 32; c++) dot += ps[t * 32 + c] * w1s[c * 16 + j];
            float z = dot * inv + b1s[j];
            acc += fmaxf(z, 0.f) * w2s[j];
        }
        out[t] = acc;
    }
}

extern "C" void kernel_launch(void* const* d_in, const int* in_sizes, int n_in,
                              void* d_out, int out_size, void* d_ws, size_t ws_size,
                              hipStream_t stream) {
    const float* x       = (const float*)d_in[0];
    const float* eattr   = (const float*)d_in[1];
    const float* e1_w1   = (const float*)d_in[2];
    const float* e1_b1   = (const float*)d_in[3];
    const float* e1_w2   = (const float*)d_in[4];
    const float* e1_b2   = (const float*)d_in[5];
    const float* root1   = (const float*)d_in[6];
    const float* bias1   = (const float*)d_in[7];
    const float* e2_w1   = (const float*)d_in[8];
    const float* e2_b1   = (const float*)d_in[9];
    const float* e2_w2   = (const float*)d_in[10];
    const float* e2_b2   = (const float*)d_in[11];
    const float* root2   = (const float*)d_in[12];
    const float* bias2   = (const float*)d_in[13];
    const float* bn1_g   = (const float*)d_in[14];
    const float* bn1_b   = (const float*)d_in[15];
    const float* bn1_m   = (const float*)d_in[16];
    const float* bn1_v   = (const float*)d_in[17];
    const float* bn2_g   = (const float*)d_in[18];
    const float* bn2_b   = (const float*)d_in[19];
    const float* bn2_m   = (const float*)d_in[20];
    const float* bn2_v   = (const float*)d_in[21];
    const float* r1_w    = (const float*)d_in[22];
    const float* r1_b    = (const float*)d_in[23];
    const float* r2_w    = (const float*)d_in[24];
    const float* r2_b    = (const float*)d_in[25];
    const int*   ei      = (const int*)d_in[26];
    const int*   batch   = (const int*)d_in[27];

    // workspace layout (bytes, 256-aligned)
    char* ws = (char*)d_ws;
    float* P    = (float*)(ws);                         // 10000*1056*4 = 42,240,000
    float* agg  = (float*)(ws + 42240000);              // 1,280,000
    float* xmid = (float*)(ws + 43520000);              // 1,280,000
    int*   cnt  = (int*)  (ws + 44800000);              // 40,000
    float* psum = (float*)(ws + 44840192);              // 8,192
    int*   pcnt = (int*)  (ws + 44848384);              // 256
    // total ~44.85 MB

    hipMemsetAsync(agg,  0, NN * 32 * 4, stream);
    hipMemsetAsync(cnt,  0, NN * 4, stream);
    hipMemsetAsync(psum, 0, GG * 32 * 4, stream);
    hipMemsetAsync(pcnt, 0, GG * 4, stream);

    k_degrees<<<(EE + 255) / 256, 256, 0, stream>>>(ei, batch, cnt, pcnt);

    // ---- layer 1 ----
    k_precompute<<<NN / 8, 256, 0, stream>>>(x, e1_w2, e1_b2, P);
    k_message<<<EE / 8, 256, 0, stream>>>(eattr, e1_w1, e1_b1, P, ei, agg);
    k_combine<<<NN / 8, 256, 0, stream>>>(x, agg, cnt, root1, bias1,
                                          bn1_g, bn1_b, bn1_m, bn1_v,
                                          xmid, nullptr, batch);

    // ---- layer 2 ----
    hipMemsetAsync(agg, 0, NN * 32 * 4, stream);
    k_precompute<<<NN / 8, 256, 0, stream>>>(xmid, e2_w2, e2_b2, P);
    k_message<<<EE / 8, 256, 0, stream>>>(eattr, e2_w1, e2_b1, P, ei, agg);
    k_combine<<<NN / 8, 256, 0, stream>>>(xmid, agg, cnt, root2, bias2,
                                          bn2_g, bn2_b, bn2_m, bn2_v,
                                          nullptr, psum, batch);

    // ---- pool + readout ----
    k_readout<<<1, 256, 0, stream>>>(psum, pcnt, r1_w, r1_b, r2_w, r2_b, (float*)d_out);
}